// Round 1
// baseline (312.830 us; speedup 1.0000x reference)
//
#include <hip/hip_runtime.h>
#include <hip/hip_bf16.h>

// SelfOtherAwareAttention: B=4, L=S=2048, D=256, H=8, hd=32
// qp/kp layout in workspace: [B*2048][512] bf16, cols 0:256 = self-proj, 256:512 = other-proj
// scale (hd^-0.5) folded into qp.

typedef __attribute__((ext_vector_type(8))) __bf16 bf16x8;
typedef __attribute__((ext_vector_type(4))) float f32x4;

#define MFMA16(a, b, c) __builtin_amdgcn_mfma_f32_16x16x32_bf16((a), (b), (c), 0, 0, 0)

__device__ __forceinline__ bf16x8 load8_f32_to_bf16(const float* __restrict__ p) {
    float4 f0 = *(const float4*)p;
    float4 f1 = *(const float4*)(p + 4);
    bf16x8 r;
    r[0] = (__bf16)f0.x; r[1] = (__bf16)f0.y; r[2] = (__bf16)f0.z; r[3] = (__bf16)f0.w;
    r[4] = (__bf16)f1.x; r[5] = (__bf16)f1.y; r[6] = (__bf16)f1.z; r[7] = (__bf16)f1.w;
    return r;
}

// ---------------- Projection: out[m, c] = (in[m,:] . W[c,:]) * scale ----------------
// W = Ws rows for c<256, Wo rows for c>=256.  M=8192, N=512, K=256.
// grid (N/64=8, M/128=64), block 256 (4 waves, 2x2 wave grid; wave tile 64x32).
__global__ __launch_bounds__(256) void proj_kernel(
    const float* __restrict__ in, const float* __restrict__ Ws,
    const float* __restrict__ Wo, __bf16* __restrict__ outp, float scale)
{
    const int n0 = blockIdx.x * 64;
    const int m0 = blockIdx.y * 128;
    const int tid  = threadIdx.x;
    const int lane = tid & 63;
    const int w    = tid >> 6;
    const int wr = w >> 1, wc = w & 1;
    const int l15 = lane & 15, l4 = lane >> 4;

    f32x4 acc[4][2];
#pragma unroll
    for (int mi = 0; mi < 4; ++mi)
#pragma unroll
        for (int ni = 0; ni < 2; ++ni) acc[mi][ni] = (f32x4){0.f, 0.f, 0.f, 0.f};

    const int arow0 = m0 + wr * 64 + l15;  // + mi*16

    // weight row pointers per ni (block/wave-uniform side selection, lane row)
    const float* wptr[2];
#pragma unroll
    for (int ni = 0; ni < 2; ++ni) {
        int c = n0 + wc * 32 + ni * 16 + l15;
        wptr[ni] = (c < 256) ? (Ws + c * 256) : (Wo + (c - 256) * 256);
    }

#pragma unroll
    for (int ks = 0; ks < 8; ++ks) {
        const int k0 = ks * 32 + l4 * 8;
        bf16x8 a[4], b[2];
#pragma unroll
        for (int mi = 0; mi < 4; ++mi)
            a[mi] = load8_f32_to_bf16(in + (arow0 + mi * 16) * 256 + k0);
#pragma unroll
        for (int ni = 0; ni < 2; ++ni)
            b[ni] = load8_f32_to_bf16(wptr[ni] + k0);
#pragma unroll
        for (int mi = 0; mi < 4; ++mi)
#pragma unroll
            for (int ni = 0; ni < 2; ++ni)
                acc[mi][ni] = MFMA16(a[mi], b[ni], acc[mi][ni]);
    }

    // epilogue: C/D layout col = lane&15, row = (lane>>4)*4 + j
#pragma unroll
    for (int mi = 0; mi < 4; ++mi)
#pragma unroll
        for (int ni = 0; ni < 2; ++ni)
#pragma unroll
            for (int j = 0; j < 4; ++j) {
                int row = m0 + wr * 64 + mi * 16 + l4 * 4 + j;
                int col = n0 + wc * 32 + ni * 16 + l15;
                outp[row * 512 + col] = (__bf16)(acc[mi][ni][j] * scale);
            }
}

// ---------------- Fused attention ----------------
// grid (S/64=32, L/128=16, B=4), block 256 (4 waves; wave owns 32 rows x 64 cols).
// Per (b, l-tile, s-tile): load mask(f32) + self_other_mask(int32) ONCE into regs
// (MFMA C/D layout), loop h=0..7: 2 MFMAs per 16x16 tile (self/other), select, add, store.
__global__ __launch_bounds__(256) void attn_kernel(
    const __bf16* __restrict__ qp, const __bf16* __restrict__ kp,
    const int* __restrict__ som, const float* __restrict__ mask,
    float* __restrict__ out)
{
    const int s0 = blockIdx.x * 64;
    const int l0 = blockIdx.y * 128;
    const int b  = blockIdx.z;
    const int tid  = threadIdx.x;
    const int lane = tid & 63;
    const int w    = tid >> 6;
    const int l15 = lane & 15, l4 = lane >> 4;

    // ---- per-block setup: mask + som in MFMA C/D layout, 32 elems/thread ----
    float mreg[32];
    unsigned int sbits = 0;
    {
        const int rbase = l0 + w * 32 + l4 * 4;  // + mi*16 + j
        const int cbase = s0 + l15;              // + ni*16
#pragma unroll
        for (int mi = 0; mi < 2; ++mi)
#pragma unroll
            for (int ni = 0; ni < 4; ++ni)
#pragma unroll
                for (int j = 0; j < 4; ++j) {
                    int idx = (b * 2048 + rbase + mi * 16 + j) * 2048 + cbase + ni * 16;
                    int t = (mi * 4 + ni) * 4 + j;
                    mreg[t] = mask[idx];
                    sbits |= (som[idx] != 0) ? (1u << t) : 0u;
                }
    }

    // fragment base pointers (A from qp rows, B from kp rows; both K-contiguous)
    const __bf16* qbase = qp + (b * 2048 + l0 + w * 32 + l15) * 512 + l4 * 8;
    const __bf16* kbase = kp + (b * 2048 + s0 + l15) * 512 + l4 * 8;

    for (int h = 0; h < 8; ++h) {
        const int hofs = h * 32;
        bf16x8 a[2][2], bb[4][2];
#pragma unroll
        for (int mi = 0; mi < 2; ++mi)
#pragma unroll
            for (int p = 0; p < 2; ++p)
                a[mi][p] = *(const bf16x8*)(qbase + mi * 16 * 512 + p * 256 + hofs);
#pragma unroll
        for (int ni = 0; ni < 4; ++ni)
#pragma unroll
            for (int p = 0; p < 2; ++p)
                bb[ni][p] = *(const bf16x8*)(kbase + ni * 16 * 512 + p * 256 + hofs);

        const int orow0 = (b * 8 + h) * 2048 + l0 + w * 32 + l4 * 4;  // + mi*16 + j
#pragma unroll
        for (int mi = 0; mi < 2; ++mi)
#pragma unroll
            for (int ni = 0; ni < 4; ++ni) {
                f32x4 z = (f32x4){0.f, 0.f, 0.f, 0.f};
                f32x4 as = MFMA16(a[mi][0], bb[ni][0], z);
                f32x4 ao = MFMA16(a[mi][1], bb[ni][1], z);
                const int t0 = (mi * 4 + ni) * 4;
                float* op = out + (orow0 + mi * 16) * 2048 + s0 + ni * 16 + l15;
#pragma unroll
                for (int j = 0; j < 4; ++j) {
                    float v = ((sbits >> (t0 + j)) & 1u) ? as[j] : ao[j];
                    op[j * 2048] = v + mreg[t0 + j];
                }
            }
    }
}

extern "C" void kernel_launch(void* const* d_in, const int* in_sizes, int n_in,
                              void* d_out, int out_size, void* d_ws, size_t ws_size,
                              hipStream_t stream) {
    const float* q    = (const float*)d_in[0];
    const float* k    = (const float*)d_in[1];
    const int*   som  = (const int*)d_in[2];
    const float* mask = (const float*)d_in[3];
    const float* Wqs  = (const float*)d_in[4];
    const float* Wqo  = (const float*)d_in[5];
    const float* Wks  = (const float*)d_in[6];
    const float* Wko  = (const float*)d_in[7];
    float* out = (float*)d_out;

    __bf16* qp = (__bf16*)d_ws;            // [8192][512]
    __bf16* kp = qp + 8192 * 512;          // [8192][512]

    dim3 pgrid(8, 64, 1), pblk(256, 1, 1);
    hipLaunchKernelGGL(proj_kernel, pgrid, pblk, 0, stream, q, Wqs, Wqo, qp,
                       0.17677669529663687f);  // 32^-0.5
    hipLaunchKernelGGL(proj_kernel, pgrid, pblk, 0, stream, k, Wks, Wko, kp, 1.0f);

    dim3 agrid(32, 16, 4), ablk(256, 1, 1);
    hipLaunchKernelGGL(attn_kernel, agrid, ablk, 0, stream, qp, kp, som, mask, out);
}

// Round 2
// 306.441 us; speedup vs baseline: 1.0209x; 1.0209x over previous
//
#include <hip/hip_runtime.h>
#include <hip/hip_bf16.h>

// SelfOtherAwareAttention: B=4, L=S=2048, D=256, H=8, hd=32
// qp/kp in workspace: [B*2048][512] bf16, cols 0:256 = self-proj, 256:512 = other-proj
// scale (hd^-0.5) folded into qp.

typedef __attribute__((ext_vector_type(8))) __bf16 bf16x8;
typedef __attribute__((ext_vector_type(4))) float f32x4;
typedef __attribute__((ext_vector_type(4))) int i32x4;

#define MFMA16(a, b, c) __builtin_amdgcn_mfma_f32_16x16x32_bf16((a), (b), (c), 0, 0, 0)

__device__ __forceinline__ bf16x8 load8_f32_to_bf16(const float* __restrict__ p) {
    float4 f0 = *(const float4*)p;
    float4 f1 = *(const float4*)(p + 4);
    bf16x8 r;
    r[0] = (__bf16)f0.x; r[1] = (__bf16)f0.y; r[2] = (__bf16)f0.z; r[3] = (__bf16)f0.w;
    r[4] = (__bf16)f1.x; r[5] = (__bf16)f1.y; r[6] = (__bf16)f1.z; r[7] = (__bf16)f1.w;
    return r;
}

// ---------------- Fused projections: q-side and k-side in one dispatch ----------------
// out[m, c] = (in[m,:] . W[c,:]) * scale ;  W = Ws rows for c<256, Wo rows for c>=256.
// Per side: M=8192, N=512, K=256. grid (8, 128): y<64 -> q side, y>=64 -> k side.
__global__ __launch_bounds__(256) void proj_kernel(
    const float* __restrict__ qin, const float* __restrict__ kin,
    const float* __restrict__ Wqs, const float* __restrict__ Wqo,
    const float* __restrict__ Wks, const float* __restrict__ Wko,
    __bf16* __restrict__ qout, __bf16* __restrict__ kout)
{
    const bool isK = blockIdx.y >= 64;
    const float* in = isK ? kin : qin;
    const float* Ws = isK ? Wks : Wqs;
    const float* Wo = isK ? Wko : Wqo;
    __bf16* outp    = isK ? kout : qout;
    const float scale = isK ? 1.0f : 0.17677669529663687f;  // 32^-0.5

    const int n0 = blockIdx.x * 64;
    const int m0 = (blockIdx.y & 63) * 128;
    const int tid  = threadIdx.x;
    const int lane = tid & 63;
    const int w    = tid >> 6;
    const int wr = w >> 1, wc = w & 1;
    const int l15 = lane & 15, l4 = lane >> 4;

    f32x4 acc[4][2];
#pragma unroll
    for (int mi = 0; mi < 4; ++mi)
#pragma unroll
        for (int ni = 0; ni < 2; ++ni) acc[mi][ni] = (f32x4){0.f, 0.f, 0.f, 0.f};

    const int arow0 = m0 + wr * 64 + l15;  // + mi*16

    const float* wptr[2];
#pragma unroll
    for (int ni = 0; ni < 2; ++ni) {
        int c = n0 + wc * 32 + ni * 16 + l15;
        wptr[ni] = (c < 256) ? (Ws + c * 256) : (Wo + (c - 256) * 256);
    }

#pragma unroll
    for (int ks = 0; ks < 8; ++ks) {
        const int k0 = ks * 32 + l4 * 8;
        bf16x8 a[4], b[2];
#pragma unroll
        for (int mi = 0; mi < 4; ++mi)
            a[mi] = load8_f32_to_bf16(in + (arow0 + mi * 16) * 256 + k0);
#pragma unroll
        for (int ni = 0; ni < 2; ++ni)
            b[ni] = load8_f32_to_bf16(wptr[ni] + k0);
#pragma unroll
        for (int mi = 0; mi < 4; ++mi)
#pragma unroll
            for (int ni = 0; ni < 2; ++ni)
                acc[mi][ni] = MFMA16(a[mi], b[ni], acc[mi][ni]);
    }

    // C/D layout: col = lane&15, row = (lane>>4)*4 + j
#pragma unroll
    for (int mi = 0; mi < 4; ++mi)
#pragma unroll
        for (int ni = 0; ni < 2; ++ni)
#pragma unroll
            for (int j = 0; j < 4; ++j) {
                int row = m0 + wr * 64 + mi * 16 + l4 * 4 + j;
                int col = n0 + wc * 32 + ni * 16 + l15;
                outp[row * 512 + col] = (__bf16)(acc[mi][ni][j] * scale);
            }
}

// ---------------- Fused attention (transposed-tile epilogue) ----------------
// grid (S/64=32, L/128=16, B=4), block 256 (4 waves; wave owns 32 l-rows x 64 s-cols).
// mfma(A=k_frag, B=q_frag): D col = lane&15 -> l, D row = (lane>>4)*4+j -> s.
// => each thread holds 4 CONSECUTIVE s values: float4 stores, float4/int4 mask loads.
__global__ __launch_bounds__(256) void attn_kernel(
    const __bf16* __restrict__ qp, const __bf16* __restrict__ kp,
    const int* __restrict__ som, const float* __restrict__ mask,
    float* __restrict__ out)
{
    const int s0 = blockIdx.x * 64;
    const int l0 = blockIdx.y * 128;
    const int b  = blockIdx.z;
    const int lane = threadIdx.x & 63;
    const int w    = threadIdx.x >> 6;
    const int l15 = lane & 15, l4 = lane >> 4;

    const int lrow0 = l0 + w * 32 + l15;   // + mi*16       (l index of this thread)
    const int scol0 = s0 + l4 * 4;         // + ni*16 (+j)  (s index, 16B aligned)

    // ---- per-block setup: mask + som in the transposed C/D layout ----
    f32x4 mreg[2][4];
    unsigned int sbits = 0;
#pragma unroll
    for (int mi = 0; mi < 2; ++mi)
#pragma unroll
        for (int ni = 0; ni < 4; ++ni) {
            int idx = (b * 2048 + lrow0 + mi * 16) * 2048 + scol0 + ni * 16;
            f32x4 m  = __builtin_nontemporal_load((const f32x4*)(mask + idx));
            i32x4 sm = __builtin_nontemporal_load((const i32x4*)(som + idx));
            mreg[mi][ni] = m;
            const int t0 = (mi * 4 + ni) * 4;
#pragma unroll
            for (int j = 0; j < 4; ++j)
                sbits |= (sm[j] != 0) ? (1u << (t0 + j)) : 0u;
        }

    // fragment bases (identical layout to before; A/B input layouts are symmetric)
    const __bf16* qbase = qp + (b * 2048 + lrow0) * 512 + l4 * 8;           // B operand (l rows)
    const __bf16* kbase = kp + (b * 2048 + s0 + l15) * 512 + l4 * 8;        // A operand (s rows)

    for (int h = 0; h < 8; ++h) {
        const int hofs = h * 32;
        bf16x8 qb[2][2], ka[4][2];
#pragma unroll
        for (int mi = 0; mi < 2; ++mi)
#pragma unroll
            for (int p = 0; p < 2; ++p)
                qb[mi][p] = *(const bf16x8*)(qbase + mi * 16 * 512 + p * 256 + hofs);
#pragma unroll
        for (int ni = 0; ni < 4; ++ni)
#pragma unroll
            for (int p = 0; p < 2; ++p)
                ka[ni][p] = *(const bf16x8*)(kbase + ni * 16 * 512 + p * 256 + hofs);

        const int obase = ((b * 8 + h) * 2048 + lrow0) * 2048 + scol0;
#pragma unroll
        for (int mi = 0; mi < 2; ++mi)
#pragma unroll
            for (int ni = 0; ni < 4; ++ni) {
                f32x4 z = (f32x4){0.f, 0.f, 0.f, 0.f};
                f32x4 as = MFMA16(ka[ni][0], qb[mi][0], z);   // self
                f32x4 ao = MFMA16(ka[ni][1], qb[mi][1], z);   // other
                const int t0 = (mi * 4 + ni) * 4;
                f32x4 v;
#pragma unroll
                for (int j = 0; j < 4; ++j)
                    v[j] = (((sbits >> (t0 + j)) & 1u) ? as[j] : ao[j]) + mreg[mi][ni][j];
                __builtin_nontemporal_store(v,
                    (f32x4*)(out + obase + mi * 16 * 2048 + ni * 16));
            }
    }
}

extern "C" void kernel_launch(void* const* d_in, const int* in_sizes, int n_in,
                              void* d_out, int out_size, void* d_ws, size_t ws_size,
                              hipStream_t stream) {
    const float* q    = (const float*)d_in[0];
    const float* k    = (const float*)d_in[1];
    const int*   som  = (const int*)d_in[2];
    const float* mask = (const float*)d_in[3];
    const float* Wqs  = (const float*)d_in[4];
    const float* Wqo  = (const float*)d_in[5];
    const float* Wks  = (const float*)d_in[6];
    const float* Wko  = (const float*)d_in[7];
    float* out = (float*)d_out;

    __bf16* qp = (__bf16*)d_ws;            // [8192][512]
    __bf16* kp = qp + 8192 * 512;          // [8192][512]

    dim3 pgrid(8, 128, 1), pblk(256, 1, 1);
    hipLaunchKernelGGL(proj_kernel, pgrid, pblk, 0, stream,
                       q, k, Wqs, Wqo, Wks, Wko, qp, kp);

    dim3 agrid(32, 16, 4), ablk(256, 1, 1);
    hipLaunchKernelGGL(attn_kernel, agrid, ablk, 0, stream, qp, kp, som, mask, out);
}

// Round 3
// 238.882 us; speedup vs baseline: 1.3096x; 1.2828x over previous
//
#include <hip/hip_runtime.h>
#include <hip/hip_bf16.h>

// SelfOtherAwareAttention: B=4, L=S=2048, D=256, H=8, hd=32
// qp/kp in workspace: [B*2048][512] bf16, cols 0:256 = self-proj, 256:512 = other-proj
// scale (hd^-0.5) folded into qp.

typedef __attribute__((ext_vector_type(8))) __bf16 bf16x8;
typedef __attribute__((ext_vector_type(4))) float f32x4;
typedef __attribute__((ext_vector_type(4))) int i32x4;

#define MFMA16(a, b, c) __builtin_amdgcn_mfma_f32_16x16x32_bf16((a), (b), (c), 0, 0, 0)

__device__ __forceinline__ bf16x8 load8_f32_to_bf16(const float* __restrict__ p) {
    float4 f0 = *(const float4*)p;
    float4 f1 = *(const float4*)(p + 4);
    bf16x8 r;
    r[0] = (__bf16)f0.x; r[1] = (__bf16)f0.y; r[2] = (__bf16)f0.z; r[3] = (__bf16)f0.w;
    r[4] = (__bf16)f1.x; r[5] = (__bf16)f1.y; r[6] = (__bf16)f1.z; r[7] = (__bf16)f1.w;
    return r;
}

// ---------------- Fused projections: q-side and k-side in one dispatch ----------------
// out[m, c] = (in[m,:] . W[c,:]) * scale ;  W = Ws rows for c<256, Wo rows for c>=256.
// Per side: M=8192, N=512, K=256. grid (8, 128): y<64 -> q side, y>=64 -> k side.
__global__ __launch_bounds__(256) void proj_kernel(
    const float* __restrict__ qin, const float* __restrict__ kin,
    const float* __restrict__ Wqs, const float* __restrict__ Wqo,
    const float* __restrict__ Wks, const float* __restrict__ Wko,
    __bf16* __restrict__ qout, __bf16* __restrict__ kout)
{
    const bool isK = blockIdx.y >= 64;
    const float* in = isK ? kin : qin;
    const float* Ws = isK ? Wks : Wqs;
    const float* Wo = isK ? Wko : Wqo;
    __bf16* outp    = isK ? kout : qout;
    const float scale = isK ? 1.0f : 0.17677669529663687f;  // 32^-0.5

    const int n0 = blockIdx.x * 64;
    const int m0 = (blockIdx.y & 63) * 128;
    const int tid  = threadIdx.x;
    const int lane = tid & 63;
    const int w    = tid >> 6;
    const int wr = w >> 1, wc = w & 1;
    const int l15 = lane & 15, l4 = lane >> 4;

    f32x4 acc[4][2];
#pragma unroll
    for (int mi = 0; mi < 4; ++mi)
#pragma unroll
        for (int ni = 0; ni < 2; ++ni) acc[mi][ni] = (f32x4){0.f, 0.f, 0.f, 0.f};

    const int arow0 = m0 + wr * 64 + l15;  // + mi*16

    const float* wptr[2];
#pragma unroll
    for (int ni = 0; ni < 2; ++ni) {
        int c = n0 + wc * 32 + ni * 16 + l15;
        wptr[ni] = (c < 256) ? (Ws + c * 256) : (Wo + (c - 256) * 256);
    }

#pragma unroll
    for (int ks = 0; ks < 8; ++ks) {
        const int k0 = ks * 32 + l4 * 8;
        bf16x8 a[4], b[2];
#pragma unroll
        for (int mi = 0; mi < 4; ++mi)
            a[mi] = load8_f32_to_bf16(in + (arow0 + mi * 16) * 256 + k0);
#pragma unroll
        for (int ni = 0; ni < 2; ++ni)
            b[ni] = load8_f32_to_bf16(wptr[ni] + k0);
#pragma unroll
        for (int mi = 0; mi < 4; ++mi)
#pragma unroll
            for (int ni = 0; ni < 2; ++ni)
                acc[mi][ni] = MFMA16(a[mi], b[ni], acc[mi][ni]);
    }

    // C/D layout: col = lane&15, row = (lane>>4)*4 + j
#pragma unroll
    for (int mi = 0; mi < 4; ++mi)
#pragma unroll
        for (int ni = 0; ni < 2; ++ni)
#pragma unroll
            for (int j = 0; j < 4; ++j) {
                int row = m0 + wr * 64 + mi * 16 + l4 * 4 + j;
                int col = n0 + wc * 32 + ni * 16 + l15;
                outp[row * 512 + col] = (__bf16)(acc[mi][ni][j] * scale);
            }
}

// ---------------- Fused attention (LDS-staged coalesced epilogue) ----------------
// grid (S/64=32, L/128=16, B=4), block 256 (4 waves; wave owns 32 l-rows x 64 s-cols).
// mfma(A=k_frag, B=q_frag): D col = lane&15 -> l, D row = (lane>>4)*4+j -> s.
// Compute tile -> LDS [128][68] -> fully-coalesced stores (256B contiguous per row,
// 4 rows per dwordx4 instruction, full 128B lines; plain cached stores).
__global__ __launch_bounds__(256) void attn_kernel(
    const __bf16* __restrict__ qp, const __bf16* __restrict__ kp,
    const int* __restrict__ som, const float* __restrict__ mask,
    float* __restrict__ out)
{
    __shared__ float tile[128][68];

    const int s0 = blockIdx.x * 64;
    const int l0 = blockIdx.y * 128;
    const int b  = blockIdx.z;
    const int tid  = threadIdx.x;
    const int lane = tid & 63;
    const int w    = tid >> 6;
    const int l15 = lane & 15, l4 = lane >> 4;

    const int lrow0 = l0 + w * 32 + l15;   // + mi*16       (l index of this thread)
    const int scol0 = s0 + l4 * 4;         // + ni*16 (+j)  (s index, 16B aligned)

    // ---- per-block setup: mask + som in the transposed C/D layout ----
    f32x4 mreg[2][4];
    unsigned int sbits = 0;
#pragma unroll
    for (int mi = 0; mi < 2; ++mi)
#pragma unroll
        for (int ni = 0; ni < 4; ++ni) {
            int idx = (b * 2048 + lrow0 + mi * 16) * 2048 + scol0 + ni * 16;
            f32x4 m  = __builtin_nontemporal_load((const f32x4*)(mask + idx));
            i32x4 sm = __builtin_nontemporal_load((const i32x4*)(som + idx));
            mreg[mi][ni] = m;
            const int t0 = (mi * 4 + ni) * 4;
#pragma unroll
            for (int j = 0; j < 4; ++j)
                sbits |= (sm[j] != 0) ? (1u << (t0 + j)) : 0u;
        }

    // fragment bases
    const __bf16* qbase = qp + (b * 2048 + lrow0) * 512 + l4 * 8;     // B operand (l rows)
    const __bf16* kbase = kp + (b * 2048 + s0 + l15) * 512 + l4 * 8;  // A operand (s rows)

    // LDS coords for compute-phase writes
    const int lds_r0 = w * 32 + l15;   // + mi*16
    const int lds_c0 = l4 * 4;         // + ni*16

    // store-phase coords (coalesced): 16 lanes = one 256B row segment
    const int st_row = tid >> 4;        // + p*16
    const int st_col = (tid & 15) * 4;

    for (int h = 0; h < 8; ++h) {
        const int hofs = h * 32;
        bf16x8 qb[2][2], ka[4][2];
#pragma unroll
        for (int mi = 0; mi < 2; ++mi)
#pragma unroll
            for (int p = 0; p < 2; ++p)
                qb[mi][p] = *(const bf16x8*)(qbase + mi * 16 * 512 + p * 256 + hofs);
#pragma unroll
        for (int ni = 0; ni < 4; ++ni)
#pragma unroll
            for (int p = 0; p < 2; ++p)
                ka[ni][p] = *(const bf16x8*)(kbase + ni * 16 * 512 + p * 256 + hofs);

#pragma unroll
        for (int mi = 0; mi < 2; ++mi)
#pragma unroll
            for (int ni = 0; ni < 4; ++ni) {
                f32x4 z = (f32x4){0.f, 0.f, 0.f, 0.f};
                f32x4 as = MFMA16(ka[ni][0], qb[mi][0], z);   // self
                f32x4 ao = MFMA16(ka[ni][1], qb[mi][1], z);   // other
                const int t0 = (mi * 4 + ni) * 4;
                f32x4 v;
#pragma unroll
                for (int j = 0; j < 4; ++j)
                    v[j] = (((sbits >> (t0 + j)) & 1u) ? as[j] : ao[j]) + mreg[mi][ni][j];
                *(f32x4*)&tile[lds_r0 + mi * 16][lds_c0 + ni * 16] = v;
            }

        __syncthreads();

        const long obase = ((long)(b * 8 + h) * 2048 + l0) * 2048 + s0;
#pragma unroll
        for (int p = 0; p < 8; ++p) {
            int r = p * 16 + st_row;
            f32x4 v = *(const f32x4*)&tile[r][st_col];
            *(f32x4*)(out + obase + (long)r * 2048 + st_col) = v;
        }

        __syncthreads();
    }
}

extern "C" void kernel_launch(void* const* d_in, const int* in_sizes, int n_in,
                              void* d_out, int out_size, void* d_ws, size_t ws_size,
                              hipStream_t stream) {
    const float* q    = (const float*)d_in[0];
    const float* k    = (const float*)d_in[1];
    const int*   som  = (const int*)d_in[2];
    const float* mask = (const float*)d_in[3];
    const float* Wqs  = (const float*)d_in[4];
    const float* Wqo  = (const float*)d_in[5];
    const float* Wks  = (const float*)d_in[6];
    const float* Wko  = (const float*)d_in[7];
    float* out = (float*)d_out;

    __bf16* qp = (__bf16*)d_ws;            // [8192][512]
    __bf16* kp = qp + 8192 * 512;          // [8192][512]

    dim3 pgrid(8, 128, 1), pblk(256, 1, 1);
    hipLaunchKernelGGL(proj_kernel, pgrid, pblk, 0, stream,
                       q, k, Wqs, Wqo, Wks, Wko, qp, kp);

    dim3 agrid(32, 16, 4), ablk(256, 1, 1);
    hipLaunchKernelGGL(attn_kernel, agrid, ablk, 0, stream, qp, kp, som, mask, out);
}